// Round 1
// baseline (505.286 us; speedup 1.0000x reference)
//
#include <hip/hip_runtime.h>

#define HW_S   65536      // 256*256 small image pixels
#define NFEAT  10
#define DIM    33
#define DIM3   35937      // 33^3
#define LUT_ELEMS (3*DIM3)
#define IMG_HW 8294400    // 2160*3840
#define IMG_ELEMS (3*IMG_HW)

// ---------------- Stage 1: per-block partial sums of gathered features ------
__global__ __launch_bounds__(256) void feat_partial(
    const int* __restrict__ msb, const int* __restrict__ lsb,
    const float* __restrict__ fm, const float* __restrict__ fl,
    float* __restrict__ partial)
{
    int p = blockIdx.x * 256 + threadIdx.x;
    int im = msb[p] * 4096 + msb[HW_S + p] * 256 + msb[2 * HW_S + p] * 16;
    int il = lsb[p] * 4096 + lsb[HW_S + p] * 256 + lsb[2 * HW_S + p] * 16;
    const float* rm = fm + im * NFEAT;
    const float* rl = fl + il * NFEAT;
    float acc[NFEAT];
#pragma unroll
    for (int f = 0; f < NFEAT; ++f) acc[f] = rm[f] + rl[f];

    // wave (64-lane) butterfly reduce each component
#pragma unroll
    for (int f = 0; f < NFEAT; ++f) {
        float v = acc[f];
#pragma unroll
        for (int off = 32; off >= 1; off >>= 1) v += __shfl_down(v, off, 64);
        acc[f] = v;
    }
    __shared__ float s[4][NFEAT];
    int lane = threadIdx.x & 63, wave = threadIdx.x >> 6;
    if (lane == 0) {
#pragma unroll
        for (int f = 0; f < NFEAT; ++f) s[wave][f] = acc[f];
    }
    __syncthreads();
    if (threadIdx.x < NFEAT) {
        float v = s[0][threadIdx.x] + s[1][threadIdx.x] + s[2][threadIdx.x] + s[3][threadIdx.x];
        partial[blockIdx.x * NFEAT + threadIdx.x] = v;
    }
}

// ---------------- Stage 2: pooled -> weights -> contracted K[c][a][w] -------
__global__ __launch_bounds__(256) void compute_K(
    const float* __restrict__ partial, const float* __restrict__ lut_cat,
    const float* __restrict__ s_layers, const float* __restrict__ luts,
    float* __restrict__ Kout)
{
    __shared__ float pooled_s[NFEAT];
    __shared__ float w_s[NFEAT];
    __shared__ float R_s[5 * 3 * NFEAT];  // [s][c][w]
    int tid = threadIdx.x;
    if (tid < NFEAT) {
        float v = 0.f;
        for (int b = 0; b < 256; ++b) v += partial[b * NFEAT + tid];
        v *= (1.0f / 65536.0f);
        v = rintf(v * 2.0f) * 0.5f;                 // round-half-even like jnp.round
        v = fminf(fmaxf(v, -16.0f), 15.5f);
        pooled_s[tid] = v;
    }
    __syncthreads();
    if (tid < NFEAT) {
        float wsum = 0.f;
        for (int i = 0; i < 5; ++i) {
            int m0 = (int)(pooled_s[2 * i] * 2.0f) + 32;
            int m1 = (int)(pooled_s[2 * i + 1] * 2.0f) + 32;
            int index = m0 * 64 + m1;
            wsum += (lut_cat[(i * 4096 + index) * NFEAT + tid] - 32.0f) * 0.25f;
        }
        w_s[tid] = wsum;
    }
    __syncthreads();
    if (tid < 150) {  // R[s][c][w] = sum_n weights[n] * luts[s*30 + n*3 + c, w]
        int w = tid % 10, sc = tid / 10, c = sc % 3, s = sc / 3;
        float r = 0.f;
        for (int n = 0; n < NFEAT; ++n)
            r += w_s[n] * luts[(s * 30 + n * 3 + c) * NFEAT + w];
        R_s[tid] = r;
    }
    __syncthreads();
    for (int t = tid; t < 3 * DIM * NFEAT; t += 256) {  // K[c][a][w]
        int w = t % 10, a = (t / 10) % DIM, c = t / (10 * DIM);
        float k = 0.f;
#pragma unroll
        for (int s = 0; s < 5; ++s)
            k += s_layers[a * 5 + s] * R_s[(s * 3 + c) * 10 + w];
        Kout[t] = k;
    }
}

// ---------------- Stage 3: materialize d3lut (second output) ----------------
__global__ __launch_bounds__(256) void compute_lut(
    const float* __restrict__ K, const float* __restrict__ w_layers,
    float* __restrict__ out_lut)
{
    int e = blockIdx.x * 256 + threadIdx.x;
    if (e >= LUT_ELEMS) return;
    int c = e / DIM3;
    int rem = e - c * DIM3;
    int i = rem / (DIM * DIM);
    int j = (rem / DIM) % DIM;
    int k = rem % DIM;
    // channel-specific axis permutation from cube_to_lut
    int a, col;
    if (c == 0)      { a = k; col = i * DIM + j; }
    else if (c == 1) { a = j; col = i * DIM + k; }
    else             { a = i; col = j * DIM + k; }
    const float* Kr = K + (c * DIM + a) * NFEAT;
    float v = 0.f;
#pragma unroll
    for (int w = 0; w < NFEAT; ++w) v = fmaf(Kr[w], w_layers[w * 1089 + col], v);
    out_lut[e] = v;
}

// ---------------- Stage 4: trilinear apply over the big image ---------------
__global__ __launch_bounds__(256) void apply_lut(
    const float* __restrict__ img, const float* __restrict__ L,
    float* __restrict__ out)
{
    constexpr float INV_BIN = 32.0f / 1.000001f;   // 1/binsize
    int t = blockIdx.x * 256 + threadIdx.x;        // 4 pixels per thread
    float4 rv = ((const float4*)img)[t];
    float4 gv = ((const float4*)(img + IMG_HW))[t];
    float4 bv = ((const float4*)(img + 2 * IMG_HW))[t];
    float rr[4] = {rv.x, rv.y, rv.z, rv.w};
    float gg[4] = {gv.x, gv.y, gv.z, gv.w};
    float bb[4] = {bv.x, bv.y, bv.z, bv.w};
    float ro[4], go[4], bo[4];
#pragma unroll
    for (int q = 0; q < 4; ++q) {
        float rf = rr[q] * INV_BIN, gf = gg[q] * INV_BIN, bf = bb[q] * INV_BIN;
        float rfl = floorf(rf), gfl = floorf(gf), bfl = floorf(bf);
        int rid = min(max((int)rfl, 0), DIM - 2);
        int gid = min(max((int)gfl, 0), DIM - 2);
        int bid = min(max((int)bfl, 0), DIM - 2);
        float rd = rf - rfl, gd = gf - gfl, bd = bf - bfl;
        float accR = 0.f, accG = 0.f, accB = 0.f;
        int base = (bid * DIM + gid) * DIM + rid;
#pragma unroll
        for (int db = 0; db < 2; ++db) {
            float wb = db ? bd : 1.0f - bd;
#pragma unroll
            for (int dg = 0; dg < 2; ++dg) {
                float w2 = wb * (dg ? gd : 1.0f - gd);
                int idx = base + (db * DIM + dg) * DIM;
                float w0 = w2 * (1.0f - rd), w1 = w2 * rd;
                accR = fmaf(w0, L[idx],            fmaf(w1, L[idx + 1],            accR));
                accG = fmaf(w0, L[DIM3 + idx],     fmaf(w1, L[DIM3 + idx + 1],     accG));
                accB = fmaf(w0, L[2 * DIM3 + idx], fmaf(w1, L[2 * DIM3 + idx + 1], accB));
            }
        }
        ro[q] = accR + rr[q]; go[q] = accG + gg[q]; bo[q] = accB + bb[q];
    }
    ((float4*)out)[t]              = make_float4(ro[0], ro[1], ro[2], ro[3]);
    ((float4*)(out + IMG_HW))[t]   = make_float4(go[0], go[1], go[2], go[3]);
    ((float4*)(out + 2 * IMG_HW))[t] = make_float4(bo[0], bo[1], bo[2], bo[3]);
}

extern "C" void kernel_launch(void* const* d_in, const int* in_sizes, int n_in,
                              void* d_out, int out_size, void* d_ws, size_t ws_size,
                              hipStream_t stream) {
    const int*   img_msb     = (const int*)d_in[0];
    const int*   img_lsb     = (const int*)d_in[1];
    const float* img_org     = (const float*)d_in[2];
    const float* feature_msb = (const float*)d_in[3];
    const float* feature_lsb = (const float*)d_in[4];
    const float* lut_cat     = (const float*)d_in[5];
    const float* s_layers    = (const float*)d_in[6];
    const float* w_layers    = (const float*)d_in[7];
    const float* luts        = (const float*)d_in[8];
    float* out = (float*)d_out;
    float* ws  = (float*)d_ws;

    float* partial = ws;         // 2560 floats (256 blocks x 10)
    float* K       = ws + 4096;  // 990 floats

    feat_partial<<<256, 256, 0, stream>>>(img_msb, img_lsb, feature_msb, feature_lsb, partial);
    compute_K<<<1, 256, 0, stream>>>(partial, lut_cat, s_layers, luts, K);
    compute_lut<<<(LUT_ELEMS + 255) / 256, 256, 0, stream>>>(K, w_layers, out + IMG_ELEMS);
    apply_lut<<<IMG_HW / 4 / 256, 256, 0, stream>>>(img_org, out + IMG_ELEMS, out);
}

// Round 2
// 230.935 us; speedup vs baseline: 2.1880x; 2.1880x over previous
//
#include <hip/hip_runtime.h>

#define HW_S   65536      // 256*256 small image pixels
#define NFEAT  10
#define DIM    33
#define DIM3   35937      // 33^3
#define LUT_ELEMS (3*DIM3)
#define IMG_HW 8294400    // 2160*3840
#define IMG_ELEMS (3*IMG_HW)

// ws layout (float indices)
#define WS_PARTIAL 0      // 2560 floats
#define WS_K       4096   // 990 floats
#define WS_AMAX    8192   // 1 uint (float bits)
#define WS_Q       8448   // 35937 uints (uchar4-packed LUT), 16B aligned

// ---------------- Stage 1: per-block partial sums of gathered features ------
__global__ __launch_bounds__(256) void feat_partial(
    const int* __restrict__ msb, const int* __restrict__ lsb,
    const float* __restrict__ fm, const float* __restrict__ fl,
    float* __restrict__ partial)
{
    int p = blockIdx.x * 256 + threadIdx.x;
    int im = msb[p] * 4096 + msb[HW_S + p] * 256 + msb[2 * HW_S + p] * 16;
    int il = lsb[p] * 4096 + lsb[HW_S + p] * 256 + lsb[2 * HW_S + p] * 16;
    const float* rm = fm + im * NFEAT;
    const float* rl = fl + il * NFEAT;
    float acc[NFEAT];
#pragma unroll
    for (int f = 0; f < NFEAT; ++f) acc[f] = rm[f] + rl[f];
#pragma unroll
    for (int f = 0; f < NFEAT; ++f) {
        float v = acc[f];
#pragma unroll
        for (int off = 32; off >= 1; off >>= 1) v += __shfl_down(v, off, 64);
        acc[f] = v;
    }
    __shared__ float s[4][NFEAT];
    int lane = threadIdx.x & 63, wave = threadIdx.x >> 6;
    if (lane == 0) {
#pragma unroll
        for (int f = 0; f < NFEAT; ++f) s[wave][f] = acc[f];
    }
    __syncthreads();
    if (threadIdx.x < NFEAT) {
        float v = s[0][threadIdx.x] + s[1][threadIdx.x] + s[2][threadIdx.x] + s[3][threadIdx.x];
        partial[blockIdx.x * NFEAT + threadIdx.x] = v;
    }
}

// ---------------- Stage 2: pooled -> weights -> contracted K[c][a][w] -------
__global__ __launch_bounds__(256) void compute_K(
    const float* __restrict__ partial, const float* __restrict__ lut_cat,
    const float* __restrict__ s_layers, const float* __restrict__ luts,
    float* __restrict__ Kout)
{
    __shared__ float pooled_s[NFEAT];
    __shared__ float w_s[NFEAT];
    __shared__ float R_s[5 * 3 * NFEAT];  // [s][c][w]
    int tid = threadIdx.x;
    if (tid < NFEAT) {
        float v = 0.f;
        for (int b = 0; b < 256; ++b) v += partial[b * NFEAT + tid];
        v *= (1.0f / 65536.0f);
        v = rintf(v * 2.0f) * 0.5f;
        v = fminf(fmaxf(v, -16.0f), 15.5f);
        pooled_s[tid] = v;
    }
    __syncthreads();
    if (tid < NFEAT) {
        float wsum = 0.f;
        for (int i = 0; i < 5; ++i) {
            int m0 = (int)(pooled_s[2 * i] * 2.0f) + 32;
            int m1 = (int)(pooled_s[2 * i + 1] * 2.0f) + 32;
            int index = m0 * 64 + m1;
            wsum += (lut_cat[(i * 4096 + index) * NFEAT + tid] - 32.0f) * 0.25f;
        }
        w_s[tid] = wsum;
    }
    __syncthreads();
    if (tid < 150) {  // R[s][c][w] = sum_n weights[n] * luts[s*30 + n*3 + c, w]
        int w = tid % 10, sc = tid / 10, c = sc % 3, s = sc / 3;
        float r = 0.f;
        for (int n = 0; n < NFEAT; ++n)
            r += w_s[n] * luts[(s * 30 + n * 3 + c) * NFEAT + w];
        R_s[tid] = r;
    }
    __syncthreads();
    for (int t = tid; t < 3 * DIM * NFEAT; t += 256) {  // K[c][a][w]
        int w = t % 10, a = (t / 10) % DIM, c = t / (10 * DIM);
        float k = 0.f;
#pragma unroll
        for (int s = 0; s < 5; ++s)
            k += s_layers[a * 5 + s] * R_s[(s * 3 + c) * 10 + w];
        Kout[t] = k;
    }
}

// ---------------- Stage 3: materialize d3lut + global absmax ----------------
__global__ __launch_bounds__(256) void compute_lut(
    const float* __restrict__ K, const float* __restrict__ w_layers,
    float* __restrict__ out_lut, unsigned int* __restrict__ amax)
{
    int e = blockIdx.x * 256 + threadIdx.x;
    float v = 0.f;
    bool valid = e < LUT_ELEMS;
    if (valid) {
        int c = e / DIM3;
        int rem = e - c * DIM3;
        int i = rem / (DIM * DIM);
        int j = (rem / DIM) % DIM;
        int k = rem % DIM;
        int a, col;
        if (c == 0)      { a = k; col = i * DIM + j; }
        else if (c == 1) { a = j; col = i * DIM + k; }
        else             { a = i; col = j * DIM + k; }
        const float* Kr = K + (c * DIM + a) * NFEAT;
#pragma unroll
        for (int w = 0; w < NFEAT; ++w) v = fmaf(Kr[w], w_layers[w * 1089 + col], v);
        out_lut[e] = v;
    }
    // block absmax -> one atomic
    float m = valid ? fabsf(v) : 0.f;
#pragma unroll
    for (int off = 32; off >= 1; off >>= 1) m = fmaxf(m, __shfl_down(m, off, 64));
    __shared__ float sm[4];
    int lane = threadIdx.x & 63, wave = threadIdx.x >> 6;
    if (lane == 0) sm[wave] = m;
    __syncthreads();
    if (threadIdx.x == 0) {
        float bm = fmaxf(fmaxf(sm[0], sm[1]), fmaxf(sm[2], sm[3]));
        atomicMax(amax, __float_as_uint(bm));
    }
}

// ---------------- Stage 4: pack LUT to interleaved int8 (uchar4/entry) ------
__global__ __launch_bounds__(256) void quantize_lut(
    const float* __restrict__ lut, const unsigned int* __restrict__ amax,
    unsigned int* __restrict__ q)
{
    int i = blockIdx.x * 256 + threadIdx.x;
    if (i >= DIM3) return;
    float am = __uint_as_float(*amax);
    float inv = 127.0f / am;
    int c0 = (int)rintf(lut[i] * inv);
    int c1 = (int)rintf(lut[DIM3 + i] * inv);
    int c2 = (int)rintf(lut[2 * DIM3 + i] * inv);
    c0 = min(max(c0, -127), 127);
    c1 = min(max(c1, -127), 127);
    c2 = min(max(c2, -127), 127);
    q[i] = (unsigned int)(c0 & 0xff) | ((unsigned int)(c1 & 0xff) << 8)
         | ((unsigned int)(c2 & 0xff) << 16);
}

// ---------------- Stage 5: trilinear apply, LUT staged in LDS ---------------
__device__ __forceinline__ float sb(unsigned int w, int b) {
    return (float)((int)(w << (24 - 8 * b)) >> 24);   // sign-extended byte b
}

__global__ __launch_bounds__(1024) void apply_lut(
    const float* __restrict__ img, const unsigned int* __restrict__ qtab,
    const unsigned int* __restrict__ amax, float* __restrict__ out)
{
    extern __shared__ unsigned int qs[];   // 35937 dwords = 143748 B
    // cooperative fill: 8984 uint4 + 1 tail dword
    for (int i = threadIdx.x; i < 8984; i += 1024)
        ((uint4*)qs)[i] = ((const uint4*)qtab)[i];
    if (threadIdx.x == 0) qs[35936] = qtab[35936];
    __syncthreads();

    float scale = __uint_as_float(*amax) * (1.0f / 127.0f);
    constexpr float INV_BIN = 32.0f / 1.000001f;
    const int ngroups = IMG_HW / 4;        // float4 groups per plane

    for (int t = blockIdx.x * 1024 + threadIdx.x; t < ngroups; t += gridDim.x * 1024) {
        float4 rv = ((const float4*)img)[t];
        float4 gv = ((const float4*)(img + IMG_HW))[t];
        float4 bv = ((const float4*)(img + 2 * IMG_HW))[t];
        float rr[4] = {rv.x, rv.y, rv.z, rv.w};
        float gg[4] = {gv.x, gv.y, gv.z, gv.w};
        float bb[4] = {bv.x, bv.y, bv.z, bv.w};
        float ro[4], go[4], bo[4];
#pragma unroll
        for (int q = 0; q < 4; ++q) {
            float rf = rr[q] * INV_BIN, gf = gg[q] * INV_BIN, bf = bb[q] * INV_BIN;
            float rfl = floorf(rf), gfl = floorf(gf), bfl = floorf(bf);
            int rid = min(max((int)rfl, 0), DIM - 2);
            int gid = min(max((int)gfl, 0), DIM - 2);
            int bid = min(max((int)bfl, 0), DIM - 2);
            float rd = rf - rfl, gd = gf - gfl, bd = bf - bfl;
            float accR = 0.f, accG = 0.f, accB = 0.f;
            int base = (bid * DIM + gid) * DIM + rid;
#pragma unroll
            for (int db = 0; db < 2; ++db) {
                float wb = db ? bd : 1.0f - bd;
#pragma unroll
                for (int dg = 0; dg < 2; ++dg) {
                    float w2 = wb * (dg ? gd : 1.0f - gd);
                    int idx = base + (db * DIM + dg) * DIM;
                    unsigned int lo = qs[idx], hi = qs[idx + 1];
                    float w0 = w2 * (1.0f - rd), w1 = w2 * rd;
                    accR = fmaf(w0, sb(lo, 0), fmaf(w1, sb(hi, 0), accR));
                    accG = fmaf(w0, sb(lo, 1), fmaf(w1, sb(hi, 1), accG));
                    accB = fmaf(w0, sb(lo, 2), fmaf(w1, sb(hi, 2), accB));
                }
            }
            ro[q] = fmaf(scale, accR, rr[q]);
            go[q] = fmaf(scale, accG, gg[q]);
            bo[q] = fmaf(scale, accB, bb[q]);
        }
        ((float4*)out)[t]                = make_float4(ro[0], ro[1], ro[2], ro[3]);
        ((float4*)(out + IMG_HW))[t]     = make_float4(go[0], go[1], go[2], go[3]);
        ((float4*)(out + 2 * IMG_HW))[t] = make_float4(bo[0], bo[1], bo[2], bo[3]);
    }
}

extern "C" void kernel_launch(void* const* d_in, const int* in_sizes, int n_in,
                              void* d_out, int out_size, void* d_ws, size_t ws_size,
                              hipStream_t stream) {
    const int*   img_msb     = (const int*)d_in[0];
    const int*   img_lsb     = (const int*)d_in[1];
    const float* img_org     = (const float*)d_in[2];
    const float* feature_msb = (const float*)d_in[3];
    const float* feature_lsb = (const float*)d_in[4];
    const float* lut_cat     = (const float*)d_in[5];
    const float* s_layers    = (const float*)d_in[6];
    const float* w_layers    = (const float*)d_in[7];
    const float* luts        = (const float*)d_in[8];
    float* out = (float*)d_out;
    float* ws  = (float*)d_ws;

    float*        partial = ws + WS_PARTIAL;
    float*        K       = ws + WS_K;
    unsigned int* amax    = (unsigned int*)(ws + WS_AMAX);
    unsigned int* q       = (unsigned int*)(ws + WS_Q);

    // allow >64KB dynamic LDS for apply_lut (idempotent, capture-safe)
    static const size_t LDS_BYTES = DIM3 * sizeof(unsigned int);  // 143748
    hipFuncSetAttribute((const void*)apply_lut,
                        hipFuncAttributeMaxDynamicSharedMemorySize, (int)LDS_BYTES);

    hipMemsetAsync(amax, 0, 4, stream);
    feat_partial<<<256, 256, 0, stream>>>(img_msb, img_lsb, feature_msb, feature_lsb, partial);
    compute_K<<<1, 256, 0, stream>>>(partial, lut_cat, s_layers, luts, K);
    compute_lut<<<(LUT_ELEMS + 255) / 256, 256, 0, stream>>>(K, w_layers, out + IMG_ELEMS, amax);
    quantize_lut<<<(DIM3 + 255) / 256, 256, 0, stream>>>(out + IMG_ELEMS, amax, q);
    apply_lut<<<512, 1024, LDS_BYTES, stream>>>(img_org, q, amax, out);
}